// Round 6
// baseline (43561.990 us; speedup 1.0000x reference)
//
#include <hip/hip_runtime.h>
#include <hip/hip_fp16.h>

// Problem dims (fixed by reference)
#define TT 256
#define BB 64
#define IN 32
#define HH 256
#define OUTD 32
#define KK 16

// Transposed f16 weight workspace (ushort offsets).
// Layout per matrix [R rows, C cols]: element (r,k) at ((k>>3)*R + r)*8 + (k&7)
// -> chunk i of row r = 8 consecutive f16 at ushort offset (i*R + r)*8.
// A wave's 64 lanes (consecutive r) read consecutive 16B chunks: fully coalesced.
#define OFF_WDX0  0
#define OFF_WDH0  (OFF_WDX0 + HH*IN)
#define OFF_WX0   (OFF_WDH0 + HH*HH)
#define OFF_WH0   (OFF_WX0  + HH*IN)
#define OFF_WO0   (OFF_WH0  + HH*HH)
#define OFF_WDX1  (OFF_WO0  + HH*HH)
#define OFF_WDH1  (OFF_WDX1 + HH*HH)
#define OFF_WX1   (OFF_WDH1 + HH*HH)
#define OFF_WH1   (OFF_WX1  + HH*HH)
#define OFF_WO1   (OFF_WH1  + HH*HH)
#define WS_TOTAL  (OFF_WO1  + OUTD*HH)   // 483328 ushorts = 944 KiB

// f32 [R,C] row-major -> f16 k-tiled transpose
__global__ void cvt_f16_T(const float* __restrict__ src, ushort* __restrict__ dst,
                          int n, int lc, int cmask, int R) {
    int tid = blockIdx.x * blockDim.x + threadIdx.x;
    int stride = gridDim.x * blockDim.x;
    for (; tid < n; tid += stride) {
        int r = tid >> lc;            // row
        int k = tid & cmask;          // col
        dst[(size_t)(((k >> 3) * R + r) * 8 + (k & 7))] =
            __half_as_ushort(__float2half_rn(src[tid]));
    }
}

__device__ __forceinline__ float2 up2(uint u) {
    union { uint u; __half2 h; } cvt;
    cvt.u = u;
    return __half22float2(cvt.h);
}

// Dot over N4*8 elements: f16 weights (global, k-tiled, coalesced) x f32 activations
// (LDS broadcast). fp32 accumulate, 4 partial accumulators.
// Chunk i covers cols k = (c0+i)*8 .. +7; ap[] must start at col c0*8.
template<int N4, int R>
__device__ __forceinline__ float dotT(const ushort* __restrict__ wbase, int r, int c0,
                                      const float* __restrict__ ap, float acc) {
    float a0 = acc, a1 = 0.f, a2 = 0.f, a3 = 0.f;
#pragma unroll
    for (int i = 0; i < N4; ++i) {
        uint4 w = *(const uint4*)(wbase + (size_t)((c0 + i) * R + r) * 8);
        float4 xlo = *(const float4*)(ap + 8 * i);
        float4 xhi = *(const float4*)(ap + 8 * i + 4);
        float2 wa;
        wa = up2(w.x); a0 = fmaf(wa.x, xlo.x, a0); a0 = fmaf(wa.y, xlo.y, a0);
        wa = up2(w.y); a1 = fmaf(wa.x, xlo.z, a1); a1 = fmaf(wa.y, xlo.w, a1);
        wa = up2(w.z); a2 = fmaf(wa.x, xhi.x, a2); a2 = fmaf(wa.y, xhi.y, a2);
        wa = up2(w.w); a3 = fmaf(wa.x, xhi.z, a3); a3 = fmaf(wa.y, xhi.w, a3);
    }
    return (a0 + a1) + (a2 + a3);
}

__device__ __forceinline__ float tanh_fast(float x) {
    x = fminf(fmaxf(x, -10.f), 10.f);
    float e = __expf(2.f * x);
    return (e - 1.f) / (e + 1.f);
}

__device__ __forceinline__ float sigmoid_half(float x) {  // 0.5*sigmoid(x)
    return 0.5f / (1.f + __expf(-x));
}

// One block per batch element. Thread h owns row h of each weight matrix.
// Activations live in LDS as f32 (broadcast reads, no bank conflicts);
// K=16 ring buffers in registers (statically indexed shift).
__global__ __launch_bounds__(256) void mrnn_persist(
    const ushort* __restrict__ ws16, const float* __restrict__ x_in,
    const float* __restrict__ bd0, const float* __restrict__ bh0, const float* __restrict__ bo0,
    const float* __restrict__ bd1, const float* __restrict__ bh1, const float* __restrict__ bo1,
    float* __restrict__ out)
{
    const int b = blockIdx.x;
    const int h = threadIdx.x;

    __shared__ __align__(16) float xs[IN];
    __shared__ __align__(16) float hp0[HH], mp0[HH], op0[HH], hp1[HH], mp1[HH];
    __shared__ float opart[OUTD * 8];

    // init state
    hp0[h] = 0.f;
    hp1[h] = 0.f;
    float buf0[KK], buf1[KK];
#pragma unroll
    for (int k = 0; k < KK; ++k) { buf0[k] = 0.f; buf1[k] = 0.f; }

    const float bd0r = bd0[h], bh0r = bh0[h], bo0r = bo0[h];
    const float bd1r = bd1[h], bh1r = bh1[h];
    const float bo1r = (h < OUTD) ? bo1[h] : 0.f;

    const ushort* wdx0b = ws16 + OFF_WDX0;
    const ushort* wdh0b = ws16 + OFF_WDH0;
    const ushort* wx0b  = ws16 + OFF_WX0;
    const ushort* wh0b  = ws16 + OFF_WH0;
    const ushort* wo0b  = ws16 + OFF_WO0;
    const ushort* wdx1b = ws16 + OFF_WDX1;
    const ushort* wdh1b = ws16 + OFF_WDH1;
    const ushort* wx1b  = ws16 + OFF_WX1;
    const ushort* wh1b  = ws16 + OFF_WH1;
    const ushort* wo1b  = ws16 + OFF_WO1;
    const int jo = h >> 3, po = h & 7;    // out1: 32 rows x 8 k-partials
    const float* xsrc = x_in + (size_t)b * IN;

    for (int t = 0; t < TT; ++t) {
        __syncthreads();                   // protect xs/opart reuse from prev iter
        if (h < IN) xs[h] = xsrc[(size_t)t * BB * IN + h];
        __syncthreads();

        // ---- layer 0: gate d ----
        float sd = dotT<IN/8, HH>(wdx0b, h, 0, xs, bd0r);
        sd = dotT<HH/8, HH>(wdh0b, h, 0, hp0, sd);
        float d = sigmoid_half(sd);        // in (0, 0.5)
        // fractional AR weights: w0=d, wk = w_{k-1} * (k-d)/(k+1)
        float w = d, m = d * buf0[0];
#pragma unroll
        for (int k = 1; k < KK; ++k) {
            const float inv = 1.f / (float)(k + 1);
            w *= fmaf(-d, inv, (float)k * inv);
            m  = fmaf(w, buf0[k], m);
        }
        mp0[h] = m;
        __syncthreads();

        // ---- layer 0: hidden + ring shift ----
        float sh = dotT<IN/8, HH>(wx0b, h, 0, xs, bh0r);
        sh = dotT<HH/8, HH>(wh0b, h, 0, mp0, sh);
        float h0 = tanh_fast(sh);
#pragma unroll
        for (int k = KK - 1; k > 0; --k) buf0[k] = buf0[k-1];
        buf0[0] = h0;
        hp0[h] = h0;
        __syncthreads();

        // ---- layer 0: output projection ----
        float so = dotT<HH/8, HH>(wo0b, h, 0, hp0, bo0r);
        op0[h] = so;
        __syncthreads();

        // ---- layer 1: gate d ----
        float sd1 = dotT<HH/8, HH>(wdx1b, h, 0, op0, bd1r);
        sd1 = dotT<HH/8, HH>(wdh1b, h, 0, hp1, sd1);
        float d1 = sigmoid_half(sd1);
        float w1 = d1, m1 = d1 * buf1[0];
#pragma unroll
        for (int k = 1; k < KK; ++k) {
            const float inv = 1.f / (float)(k + 1);
            w1 *= fmaf(-d1, inv, (float)k * inv);
            m1  = fmaf(w1, buf1[k], m1);
        }
        mp1[h] = m1;
        __syncthreads();

        // ---- layer 1: hidden + ring shift ----
        float sh1 = dotT<HH/8, HH>(wx1b, h, 0, op0, bh1r);
        sh1 = dotT<HH/8, HH>(wh1b, h, 0, mp1, sh1);
        float h1 = tanh_fast(sh1);
#pragma unroll
        for (int k = KK - 1; k > 0; --k) buf1[k] = buf1[k-1];
        buf1[0] = h1;
        hp1[h] = h1;
        __syncthreads();

        // ---- layer 1: output (32 rows x 8 k-partials) ----
        float p = dotT<4, OUTD>(wo1b, jo, po * 4, hp1 + po * 32, 0.f);
        opart[h] = p;                      // h == jo*8+po
        __syncthreads();
        if (h < OUTD) {
            const float* q = opart + h * 8;
            float s = bo1r + ((q[0] + q[1]) + (q[2] + q[3])) + ((q[4] + q[5]) + (q[6] + q[7]));
            out[(size_t)(t * BB + b) * OUTD + h] = s;
        }
    }
}

extern "C" void kernel_launch(void* const* d_in, const int* in_sizes, int n_in,
                              void* d_out, int out_size, void* d_ws, size_t ws_size,
                              hipStream_t stream) {
    const float* inputs = (const float*)d_in[0];
    const float* Wdx0 = (const float*)d_in[1];
    const float* Wdh0 = (const float*)d_in[2];
    const float* bd0  = (const float*)d_in[3];
    const float* Wx0  = (const float*)d_in[4];
    const float* Wh0  = (const float*)d_in[5];
    const float* bh0  = (const float*)d_in[6];
    const float* Wo0  = (const float*)d_in[7];
    const float* bo0  = (const float*)d_in[8];
    const float* Wdx1 = (const float*)d_in[9];
    const float* Wdh1 = (const float*)d_in[10];
    const float* bd1  = (const float*)d_in[11];
    const float* Wx1  = (const float*)d_in[12];
    const float* Wh1  = (const float*)d_in[13];
    const float* bh1  = (const float*)d_in[14];
    const float* Wo1  = (const float*)d_in[15];
    const float* bo1  = (const float*)d_in[16];

    ushort* ws16 = (ushort*)d_ws;

    // src, dst offset, n, lc(log2 C), cmask(C-1), R(rows)
    struct Seg { const float* src; int off, n, lc, cmask, R; };
    const Seg segs[10] = {
        { Wdx0, OFF_WDX0, HH*IN, 5,  31,  HH },
        { Wdh0, OFF_WDH0, HH*HH, 8,  255, HH },
        { Wx0,  OFF_WX0,  HH*IN, 5,  31,  HH },
        { Wh0,  OFF_WH0,  HH*HH, 8,  255, HH },
        { Wo0,  OFF_WO0,  HH*HH, 8,  255, HH },
        { Wdx1, OFF_WDX1, HH*HH, 8,  255, HH },
        { Wdh1, OFF_WDH1, HH*HH, 8,  255, HH },
        { Wx1,  OFF_WX1,  HH*HH, 8,  255, HH },
        { Wh1,  OFF_WH1,  HH*HH, 8,  255, HH },
        { Wo1,  OFF_WO1,  OUTD*HH, 8, 255, OUTD },
    };
    for (int i = 0; i < 10; ++i) {
        int blocks = (segs[i].n + 255) / 256;
        if (blocks > 512) blocks = 512;
        hipLaunchKernelGGL(cvt_f16_T, dim3(blocks), dim3(256), 0, stream,
                           segs[i].src, ws16 + segs[i].off,
                           segs[i].n, segs[i].lc, segs[i].cmask, segs[i].R);
    }

    hipLaunchKernelGGL(mrnn_persist, dim3(BB), dim3(256), 0, stream,
                       (const ushort*)ws16, inputs,
                       bd0, bh0, bo0, bd1, bh1, bo1, (float*)d_out);
}

// Round 8
// 10378.296 us; speedup vs baseline: 4.1974x; 4.1974x over previous
//
#include <hip/hip_runtime.h>
#include <hip/hip_fp16.h>

// Problem dims (fixed by reference)
#define TT 256
#define BB 64
#define IN 32
#define HH 256
#define OUTD 32
#define KK 16
#define NB 8              // batches per block
#define NBLK (BB/NB)      // 8 blocks -> 1 per XCD, exclusive L2
#define NT 1024           // 16 waves: thread = (q = k-quarter, r = row)

// k-tiled transposed f16 weight layout (ushort offsets), same as prior round:
// element (r,k) of [R,C] matrix at ((k>>3)*R + r)*8 + (k&7)
// -> chunk c=k>>3 of row r = 16B at ((c*R + r)*16B), wave-coalesced across r.
#define OFF_WDX0  0
#define OFF_WDH0  (OFF_WDX0 + HH*IN)
#define OFF_WX0   (OFF_WDH0 + HH*HH)
#define OFF_WH0   (OFF_WX0  + HH*IN)
#define OFF_WO0   (OFF_WH0  + HH*HH)
#define OFF_WDX1  (OFF_WO0  + HH*HH)
#define OFF_WDH1  (OFF_WDX1 + HH*HH)
#define OFF_WX1   (OFF_WDH1 + HH*HH)
#define OFF_WH1   (OFF_WX1  + HH*HH)
#define OFF_WO1   (OFF_WH1  + HH*HH)

__global__ void cvt_f16_T(const float* __restrict__ src, ushort* __restrict__ dst,
                          int n, int lc, int cmask, int R) {
    int tid = blockIdx.x * blockDim.x + threadIdx.x;
    int stride = gridDim.x * blockDim.x;
    for (; tid < n; tid += stride) {
        int r = tid >> lc;            // row
        int k = tid & cmask;          // col
        dst[(size_t)(((k >> 3) * R + r) * 8 + (k & 7))] =
            __half_as_ushort(__float2half_rn(src[tid]));
    }
}

typedef _Float16 h2v __attribute__((ext_vector_type(2)));

// acc += w.lo*a.lo + w.hi*a.hi  (f16 pairs, f32 accumulate)
__device__ __forceinline__ float dot2acc(float acc, uint w, uint a) {
#if __has_builtin(__builtin_amdgcn_fdot2)
    union { uint u; h2v h; } W, A;
    W.u = w; A.u = a;
    return __builtin_amdgcn_fdot2(W.h, A.h, acc, false);
#else
    union { uint u; _Float16 f[2]; } W, A;
    W.u = w; A.u = a;
    acc = fmaf((float)W.f[0], (float)A.f[0], acc);
    return fmaf((float)W.f[1], (float)A.f[1], acc);
#endif
}

__device__ __forceinline__ float2 uph(uint u) {
    union { uint u; _Float16 f[2]; } c; c.u = u;
    return make_float2((float)c.f[0], (float)c.f[1]);
}
__device__ __forceinline__ uint packh2(float a, float b) {
    union { uint u; _Float16 f[2]; } c;
    c.f[0] = (_Float16)a; c.f[1] = (_Float16)b;
    return c.u;
}

__device__ __forceinline__ float tanh_fast(float x) {
    x = fminf(fmaxf(x, -10.f), 10.f);
    float e = __expf(2.f * x);
    return (e - 1.f) / (e + 1.f);
}
__device__ __forceinline__ float sigmoid_half(float x) {  // 0.5*sigmoid(x)
    return 0.5f / (1.f + __expf(-x));
}

// Partial dot for NCH 8-k chunks starting at chunk c0, rows of W from global
// (k-tiled layout, R rows), activations from LDS actQ[k2][8 batches] (k-paired
// half2 per batch, broadcast reads). p[8] accumulates f32 per batch.
template<int NCH, int R>
__device__ __forceinline__ void dotSlice(const ushort* __restrict__ wb, int row, int c0,
                                         const uint* actQ, float p[NB]) {
#pragma unroll
    for (int i = 0; i < NCH; ++i) {
        const int c = c0 + i;
        uint4 w = *(const uint4*)(wb + (size_t)(c * R + row) * 8);
#pragma unroll
        for (int j = 0; j < 4; ++j) {
            const uint* a = actQ + (size_t)(c * 4 + j) * 8;
            uint4 A0 = *(const uint4*)(a);
            uint4 A1 = *(const uint4*)(a + 4);
            const uint wj = (j == 0) ? w.x : (j == 1) ? w.y : (j == 2) ? w.z : w.w;
            p[0] = dot2acc(p[0], wj, A0.x);
            p[1] = dot2acc(p[1], wj, A0.y);
            p[2] = dot2acc(p[2], wj, A0.z);
            p[3] = dot2acc(p[3], wj, A0.w);
            p[4] = dot2acc(p[4], wj, A1.x);
            p[5] = dot2acc(p[5], wj, A1.y);
            p[6] = dot2acc(p[6], wj, A1.z);
            p[7] = dot2acc(p[7], wj, A1.w);
        }
    }
}

// Repack per-thread (b0,b1) half2 for row r into k-paired act layout:
// actQ[r/2][2bp] = (v_r[b0], v_{r+1}[b0]); actQ[r/2][2bp+1] = (v_r[b1], v_{r+1}[b1])
__device__ __forceinline__ void repack(uint pr, int r, int bp, uint* dst) {
    uint nb = __shfl_down(pr, 1);            // from row r+1 (same wave)
    if (!(r & 1)) {
        dst[(r >> 1) * 8 + 2 * bp]     = (pr & 0xffffu) | (nb << 16);
        dst[(r >> 1) * 8 + 2 * bp + 1] = (pr >> 16) | (nb & 0xffff0000u);
    }
}

#define PIDX(q, rr, b)  ((((q) << 8) + (rr)) * 9 + (b))
#define P6IDX(c, rw, b) ((((c) << 5) + (rw)) * 9 + (b))

__global__ __launch_bounds__(NT) void mrnn_persist(
    const ushort* __restrict__ ws16, const float* __restrict__ x_in,
    const float* __restrict__ bd0, const float* __restrict__ bh0, const float* __restrict__ bo0,
    const float* __restrict__ bd1, const float* __restrict__ bh1, const float* __restrict__ bo1,
    float* __restrict__ out)
{
    const int g   = blockIdx.x;
    const int tid = threadIdx.x;
    const int r   = tid & 255;      // row (dots over H-matrices; epilogue row)
    const int bp  = tid >> 8;       // k-quarter for dots == batch-pair for epilogue
    const int r6  = tid & 31;       // Wo1 row
    const int c6  = tid >> 5;       // Wo1 k-chunk

    __shared__ uint  actx[16 * 8];                                   // x, k-paired
    __shared__ uint  acth0[128 * 8], actm[128 * 8], acto[128 * 8], acth1[128 * 8];
    __shared__ float part[4 * 256 * 9];                              // q-partials (padded)

    acth0[tid] = 0;
    acth1[tid] = 0;

    uint rb0[KK], rb1[KK];          // K=16 rings, (b0,b1) f16 pairs per slot
#pragma unroll
    for (int k = 0; k < KK; ++k) { rb0[k] = 0; rb1[k] = 0; }

    const float bd0r = bd0[r], bh0r = bh0[r], bo0r = bo0[r];
    const float bd1r = bd1[r], bh1r = bh1[r];
    const float bo1r = bo1[r6];

    const ushort* wdx0b = ws16 + OFF_WDX0;
    const ushort* wdh0b = ws16 + OFF_WDH0;
    const ushort* wx0b  = ws16 + OFF_WX0;
    const ushort* wh0b  = ws16 + OFF_WH0;
    const ushort* wo0b  = ws16 + OFF_WO0;
    const ushort* wdx1b = ws16 + OFF_WDX1;
    const ushort* wdh1b = ws16 + OFF_WDH1;
    const ushort* wx1b  = ws16 + OFF_WX1;
    const ushort* wh1b  = ws16 + OFF_WH1;
    const ushort* wo1b  = ws16 + OFF_WO1;

    for (int t = 0; t < TT; ++t) {
        __syncthreads();                       // part/actx safe to overwrite
        // ---- stage x_t (f32 global -> k-paired f16 LDS) ----
        if (tid < 128) {
            const int k = tid & 31, xp = tid >> 5;
            const int b0 = g * NB + 2 * xp;
            float xa = x_in[(size_t)(t * BB + b0) * IN + k];
            float xb = x_in[(size_t)(t * BB + b0 + 1) * IN + k];
            uint pr = packh2(xa, xb);
            uint nb = __shfl_down(pr, 1);
            if (!(k & 1)) {
                actx[(k >> 1) * 8 + 2 * xp]     = (pr & 0xffffu) | (nb << 16);
                actx[(k >> 1) * 8 + 2 * xp + 1] = (pr >> 16) | (nb & 0xffff0000u);
            }
        }
        __syncthreads();

        float p[NB];

        // ---- phase 1: gate0  (Wdx0@x + Wdh0@h0_prev) ----
#pragma unroll
        for (int b = 0; b < NB; ++b) p[b] = 0.f;
        dotSlice<1, HH>(wdx0b, r, bp, actx, p);
        dotSlice<8, HH>(wdh0b, r, bp * 8, acth0, p);
#pragma unroll
        for (int b = 0; b < NB; ++b) part[PIDX(bp, r, b)] = p[b];
        __syncthreads();
        {   // epilogue: d, fractional weights, memory term m
            float s0 = bd0r, s1 = bd0r;
#pragma unroll
            for (int q = 0; q < 4; ++q) {
                s0 += part[PIDX(q, r, 2 * bp)];
                s1 += part[PIDX(q, r, 2 * bp + 1)];
            }
            float d0 = sigmoid_half(s0), d1 = sigmoid_half(s1);
            float w0 = d0, w1 = d1;
            float2 f = uph(rb0[0]);
            float m0 = d0 * f.x, m1 = d1 * f.y;
#pragma unroll
            for (int k = 1; k < KK; ++k) {
                const float inv = 1.f / (float)(k + 1);
                const float base = (float)k * inv;
                w0 *= fmaf(-d0, inv, base);
                w1 *= fmaf(-d1, inv, base);
                f = uph(rb0[k]);
                m0 = fmaf(w0, f.x, m0);
                m1 = fmaf(w1, f.y, m1);
            }
            repack(packh2(m0, m1), r, bp, actm);
        }
        __syncthreads();

        // ---- phase 2: hidden0  (Wx0@x + Wh0@m) ----
#pragma unroll
        for (int b = 0; b < NB; ++b) p[b] = 0.f;
        dotSlice<1, HH>(wx0b, r, bp, actx, p);
        dotSlice<8, HH>(wh0b, r, bp * 8, actm, p);
#pragma unroll
        for (int b = 0; b < NB; ++b) part[PIDX(bp, r, b)] = p[b];
        __syncthreads();
        {   // epilogue: tanh, ring push, publish h0
            float s0 = bh0r, s1 = bh0r;
#pragma unroll
            for (int q = 0; q < 4; ++q) {
                s0 += part[PIDX(q, r, 2 * bp)];
                s1 += part[PIDX(q, r, 2 * bp + 1)];
            }
            float h00 = tanh_fast(s0), h01 = tanh_fast(s1);
#pragma unroll
            for (int k = KK - 1; k > 0; --k) rb0[k] = rb0[k - 1];
            rb0[0] = packh2(h00, h01);
            repack(rb0[0], r, bp, acth0);
        }
        __syncthreads();

        // ---- phase 3: out0  (Wo0@h0 + bo0) ----
#pragma unroll
        for (int b = 0; b < NB; ++b) p[b] = 0.f;
        dotSlice<8, HH>(wo0b, r, bp * 8, acth0, p);
#pragma unroll
        for (int b = 0; b < NB; ++b) part[PIDX(bp, r, b)] = p[b];
        __syncthreads();
        {
            float s0 = bo0r, s1 = bo0r;
#pragma unroll
            for (int q = 0; q < 4; ++q) {
                s0 += part[PIDX(q, r, 2 * bp)];
                s1 += part[PIDX(q, r, 2 * bp + 1)];
            }
            repack(packh2(s0, s1), r, bp, acto);
        }
        __syncthreads();

        // ---- phase 4: gate1  (Wdx1@o0 + Wdh1@h1_prev) ----
#pragma unroll
        for (int b = 0; b < NB; ++b) p[b] = 0.f;
        dotSlice<8, HH>(wdx1b, r, bp * 8, acto, p);
        dotSlice<8, HH>(wdh1b, r, bp * 8, acth1, p);
#pragma unroll
        for (int b = 0; b < NB; ++b) part[PIDX(bp, r, b)] = p[b];
        __syncthreads();
        {
            float s0 = bd1r, s1 = bd1r;
#pragma unroll
            for (int q = 0; q < 4; ++q) {
                s0 += part[PIDX(q, r, 2 * bp)];
                s1 += part[PIDX(q, r, 2 * bp + 1)];
            }
            float d0 = sigmoid_half(s0), d1 = sigmoid_half(s1);
            float w0 = d0, w1 = d1;
            float2 f = uph(rb1[0]);
            float m0 = d0 * f.x, m1 = d1 * f.y;
#pragma unroll
            for (int k = 1; k < KK; ++k) {
                const float inv = 1.f / (float)(k + 1);
                const float base = (float)k * inv;
                w0 *= fmaf(-d0, inv, base);
                w1 *= fmaf(-d1, inv, base);
                f = uph(rb1[k]);
                m0 = fmaf(w0, f.x, m0);
                m1 = fmaf(w1, f.y, m1);
            }
            repack(packh2(m0, m1), r, bp, actm);
        }
        __syncthreads();

        // ---- phase 5: hidden1  (Wx1@o0 + Wh1@m1) ----
#pragma unroll
        for (int b = 0; b < NB; ++b) p[b] = 0.f;
        dotSlice<8, HH>(wx1b, r, bp * 8, acto, p);
        dotSlice<8, HH>(wh1b, r, bp * 8, actm, p);
#pragma unroll
        for (int b = 0; b < NB; ++b) part[PIDX(bp, r, b)] = p[b];
        __syncthreads();
        {
            float s0 = bh1r, s1 = bh1r;
#pragma unroll
            for (int q = 0; q < 4; ++q) {
                s0 += part[PIDX(q, r, 2 * bp)];
                s1 += part[PIDX(q, r, 2 * bp + 1)];
            }
            float h10 = tanh_fast(s0), h11 = tanh_fast(s1);
#pragma unroll
            for (int k = KK - 1; k > 0; --k) rb1[k] = rb1[k - 1];
            rb1[0] = packh2(h10, h11);
            repack(rb1[0], r, bp, acth1);
        }
        __syncthreads();

        // ---- phase 6: out1  (Wo1@h1 + bo1), 32 rows x 32 k-chunks ----
#pragma unroll
        for (int b = 0; b < NB; ++b) p[b] = 0.f;
        dotSlice<1, OUTD>(wo1b, r6, c6, acth1, p);
#pragma unroll
        for (int b = 0; b < NB; ++b) part[P6IDX(c6, r6, b)] = p[b];
        __syncthreads();
        if (tid < 128) {
            const int xp = tid >> 5;
            float s0 = bo1r, s1 = bo1r;
#pragma unroll
            for (int c = 0; c < 32; ++c) {
                s0 += part[P6IDX(c, r6, 2 * xp)];
                s1 += part[P6IDX(c, r6, 2 * xp + 1)];
            }
            const int b0 = g * NB + 2 * xp;
            out[(size_t)(t * BB + b0) * OUTD + r6]     = s0;
            out[(size_t)(t * BB + b0 + 1) * OUTD + r6] = s1;
        }
    }
}

extern "C" void kernel_launch(void* const* d_in, const int* in_sizes, int n_in,
                              void* d_out, int out_size, void* d_ws, size_t ws_size,
                              hipStream_t stream) {
    const float* inputs = (const float*)d_in[0];
    const float* Wdx0 = (const float*)d_in[1];
    const float* Wdh0 = (const float*)d_in[2];
    const float* bd0  = (const float*)d_in[3];
    const float* Wx0  = (const float*)d_in[4];
    const float* Wh0  = (const float*)d_in[5];
    const float* bh0  = (const float*)d_in[6];
    const float* Wo0  = (const float*)d_in[7];
    const float* bo0  = (const float*)d_in[8];
    const float* Wdx1 = (const float*)d_in[9];
    const float* Wdh1 = (const float*)d_in[10];
    const float* bd1  = (const float*)d_in[11];
    const float* Wx1  = (const float*)d_in[12];
    const float* Wh1  = (const float*)d_in[13];
    const float* bh1  = (const float*)d_in[14];
    const float* Wo1  = (const float*)d_in[15];
    const float* bo1  = (const float*)d_in[16];

    ushort* ws16 = (ushort*)d_ws;

    struct Seg { const float* src; int off, n, lc, cmask, R; };
    const Seg segs[10] = {
        { Wdx0, OFF_WDX0, HH*IN, 5,  31,  HH },
        { Wdh0, OFF_WDH0, HH*HH, 8,  255, HH },
        { Wx0,  OFF_WX0,  HH*IN, 5,  31,  HH },
        { Wh0,  OFF_WH0,  HH*HH, 8,  255, HH },
        { Wo0,  OFF_WO0,  HH*HH, 8,  255, HH },
        { Wdx1, OFF_WDX1, HH*HH, 8,  255, HH },
        { Wdh1, OFF_WDH1, HH*HH, 8,  255, HH },
        { Wx1,  OFF_WX1,  HH*HH, 8,  255, HH },
        { Wh1,  OFF_WH1,  HH*HH, 8,  255, HH },
        { Wo1,  OFF_WO1,  OUTD*HH, 8, 255, OUTD },
    };
    for (int i = 0; i < 10; ++i) {
        int blocks = (segs[i].n + 255) / 256;
        if (blocks > 512) blocks = 512;
        hipLaunchKernelGGL(cvt_f16_T, dim3(blocks), dim3(256), 0, stream,
                           segs[i].src, ws16 + segs[i].off,
                           segs[i].n, segs[i].lc, segs[i].cmask, segs[i].R);
    }

    hipLaunchKernelGGL(mrnn_persist, dim3(NBLK), dim3(NT), 0, stream,
                       (const ushort*)ws16, inputs,
                       bd0, bh0, bo0, bd1, bh1, bo1, (float*)d_out);
}

// Round 10
// 9485.207 us; speedup vs baseline: 4.5926x; 1.0942x over previous
//
#include <hip/hip_runtime.h>
#include <hip/hip_fp16.h>

// Problem dims (fixed by reference)
#define TT 256
#define BB 64
#define IN 32
#define HH 256
#define OUTD 32
#define KK 16
#define NB 8              // batches per block
#define NBLK (BB/NB)      // 8 blocks -> 1 per XCD, exclusive L2
#define NT 1024           // 16 waves; lane = (q = k-quarter, rl = row-in-wave)

// k-tiled transposed f16 weight layout (ushort offsets):
// element (r,k) of [R,C] matrix at ((k>>3)*R + r)*8 + (k&7)
// -> chunk c=k>>3 of row r = 16B at ((c*R + r)*16B), coalesced across r.
#define OFF_WDX0  0
#define OFF_WDH0  (OFF_WDX0 + HH*IN)
#define OFF_WX0   (OFF_WDH0 + HH*HH)
#define OFF_WH0   (OFF_WX0  + HH*IN)
#define OFF_WO0   (OFF_WH0  + HH*HH)
#define OFF_WDX1  (OFF_WO0  + HH*HH)
#define OFF_WDH1  (OFF_WDX1 + HH*HH)
#define OFF_WX1   (OFF_WDH1 + HH*HH)
#define OFF_WH1   (OFF_WX1  + HH*HH)
#define OFF_WO1   (OFF_WH1  + HH*HH)

// Act LDS layout (uint = k-paired f16 for one batch):
// H-acts: addr(k2, b) = (k2>>5)*264 + (k2&31)*8 + b   (264 = 8*32 + 8 pad
//   -> the 4 q-regions start 8 banks apart: conflict-free 4-address reads)
// x: addr(k2, b) = (k2>>2)*36 + (k2&3)*8 + b
#define HSTRIDE 264
#define XSTRIDE 36

__global__ void cvt_f16_T(const float* __restrict__ src, ushort* __restrict__ dst,
                          int n, int lc, int cmask, int R) {
    int tid = blockIdx.x * blockDim.x + threadIdx.x;
    int stride = gridDim.x * blockDim.x;
    for (; tid < n; tid += stride) {
        int r = tid >> lc;            // row
        int k = tid & cmask;          // col
        dst[(size_t)(((k >> 3) * R + r) * 8 + (k & 7))] =
            __half_as_ushort(__float2half_rn(src[tid]));
    }
}

typedef _Float16 h2v __attribute__((ext_vector_type(2)));

__device__ __forceinline__ float dot2acc(float acc, uint w, uint a) {
#if __has_builtin(__builtin_amdgcn_fdot2)
    union { uint u; h2v h; } W, A;
    W.u = w; A.u = a;
    return __builtin_amdgcn_fdot2(W.h, A.h, acc, false);
#else
    union { uint u; _Float16 f[2]; } W, A;
    W.u = w; A.u = a;
    acc = fmaf((float)W.f[0], (float)A.f[0], acc);
    return fmaf((float)W.f[1], (float)A.f[1], acc);
#endif
}

__device__ __forceinline__ float2 uph(uint u) {
    union { uint u; _Float16 f[2]; } c; c.u = u;
    return make_float2((float)c.f[0], (float)c.f[1]);
}
__device__ __forceinline__ uint packh2(float a, float b) {
    union { uint u; _Float16 f[2]; } c;
    c.f[0] = (_Float16)a; c.f[1] = (_Float16)b;
    return c.u;
}

__device__ __forceinline__ float tanh_fast(float x) {
    x = fminf(fmaxf(x, -10.f), 10.f);
    float e = __expf(2.f * x);
    return (e - 1.f) / (e + 1.f);
}
__device__ __forceinline__ float sigmoid_half(float x) {  // 0.5*sigmoid(x)
    return 0.5f / (1.f + __expf(-x));
}

__device__ __forceinline__ void dots8(uint wj, const uint* a, float p[NB]) {
    uint4 A0 = *(const uint4*)(a);
    uint4 A1 = *(const uint4*)(a + 4);
    p[0] = dot2acc(p[0], wj, A0.x);
    p[1] = dot2acc(p[1], wj, A0.y);
    p[2] = dot2acc(p[2], wj, A0.z);
    p[3] = dot2acc(p[3], wj, A0.w);
    p[4] = dot2acc(p[4], wj, A1.x);
    p[5] = dot2acc(p[5], wj, A1.y);
    p[6] = dot2acc(p[6], wj, A1.z);
    p[7] = dot2acc(p[7], wj, A1.w);
}

// 8-chunk slice of an H-col matrix: lane (q,r) covers chunks q*8..q*8+7 of row r.
// Weight loads hoisted into w[8] (independent; compiler issues back-to-back).
template<int R>
__device__ __forceinline__ void dotH(const ushort* __restrict__ wb, int r, int q,
                                     const uint* act, float p[NB]) {
    uint4 w[8];
#pragma unroll
    for (int i = 0; i < 8; ++i)
        w[i] = *(const uint4*)(wb + (size_t)((q * 8 + i) * R + r) * 8);
#pragma unroll
    for (int i = 0; i < 8; ++i) {
        const uint* areg = act + q * HSTRIDE + i * 32;
        dots8(w[i].x, areg, p);
        dots8(w[i].y, areg + 8, p);
        dots8(w[i].z, areg + 16, p);
        dots8(w[i].w, areg + 24, p);
    }
}

// single x-chunk (IN=32: chunk c == q)
__device__ __forceinline__ void dotX(const ushort* __restrict__ wb, int r, int q,
                                     const uint* actx, float p[NB]) {
    uint4 w = *(const uint4*)(wb + (size_t)(q * HH + r) * 8);
    const uint* areg = actx + q * XSTRIDE;
    dots8(w.x, areg, p);
    dots8(w.y, areg + 8, p);
    dots8(w.z, areg + 16, p);
    dots8(w.w, areg + 24, p);
}

__device__ __forceinline__ void bfly(float p[NB]) {
#pragma unroll
    for (int b = 0; b < NB; ++b) {
        p[b] += __shfl_xor(p[b], 16);
        p[b] += __shfl_xor(p[b], 32);
    }
}

// even-row lanes pack (v_r, v_{r+1}) pairs for their 2 batches into act LDS
__device__ __forceinline__ void repack(uint pr, int r, int q, uint* dst) {
    uint nb = __shfl_down(pr, 1);           // row r+1, same q-group, same wave
    if (!(r & 1)) {
        int k2 = r >> 1;
        uint* a = dst + (k2 >> 5) * HSTRIDE + (k2 & 31) * 8 + 2 * q;
        a[0] = (pr & 0xffffu) | (nb << 16);
        a[1] = (pr >> 16) | (nb & 0xffff0000u);
    }
}

__global__ __launch_bounds__(NT, 4) void mrnn_persist(
    const ushort* __restrict__ ws16, const float* __restrict__ x_in,
    const float* __restrict__ bd0, const float* __restrict__ bh0, const float* __restrict__ bo0,
    const float* __restrict__ bd1, const float* __restrict__ bh1, const float* __restrict__ bo1,
    float* __restrict__ out)
{
    const int g    = blockIdx.x;
    const int tid  = threadIdx.x;
    const int wave = tid >> 6;
    const int lane = tid & 63;
    const int q    = lane >> 4;       // k-quarter AND batch-pair owner
    const int rl   = lane & 15;
    const int r    = wave * 16 + rl;  // row 0..255
    const int r6   = wave * 2 + (lane >> 5);   // Wo1 row 0..31
    const int c6   = lane & 31;                // Wo1 k-chunk 0..31

    __shared__ uint actx[4 * XSTRIDE];
    __shared__ uint acth0[4 * HSTRIDE], actm[4 * HSTRIDE];
    __shared__ uint acto[4 * HSTRIDE], acth1[4 * HSTRIDE];

    for (int i = tid; i < 4 * HSTRIDE; i += NT) { acth0[i] = 0; acth1[i] = 0; }

    uint rb0[KK], rb1[KK];            // rings: (b0,b1) f16 pairs, static-indexed
#pragma unroll
    for (int k = 0; k < KK; ++k) { rb0[k] = 0; rb1[k] = 0; }

    const float bd0r = bd0[r], bh0r = bh0[r], bo0r = bo0[r];
    const float bd1r = bd1[r], bh1r = bh1[r];
    const float bo1r = bo1[r6];

    const ushort* wdx0b = ws16 + OFF_WDX0;
    const ushort* wdh0b = ws16 + OFF_WDH0;
    const ushort* wx0b  = ws16 + OFF_WX0;
    const ushort* wh0b  = ws16 + OFF_WH0;
    const ushort* wo0b  = ws16 + OFF_WO0;
    const ushort* wdx1b = ws16 + OFF_WDX1;
    const ushort* wdh1b = ws16 + OFF_WDH1;
    const ushort* wx1b  = ws16 + OFF_WX1;
    const ushort* wh1b  = ws16 + OFF_WH1;
    const ushort* wo1b  = ws16 + OFF_WO1;

    for (int t = 0; t < TT; ++t) {
        // ---- stage x_t ----
        if (tid < 128) {
            const int b = tid & 7, k2 = tid >> 3;     // k2 0..15
            const int gb = g * NB + b;
            float x0 = x_in[((size_t)t * BB + gb) * IN + 2 * k2];
            float x1 = x_in[((size_t)t * BB + gb) * IN + 2 * k2 + 1];
            actx[(k2 >> 2) * XSTRIDE + (k2 & 3) * 8 + b] = packh2(x0, x1);
        }
        __syncthreads();

        float p[NB];

        // ---- P1: gate0 = Wdx0@x + Wdh0@h0_prev ----
#pragma unroll
        for (int b = 0; b < NB; ++b) p[b] = 0.f;
        dotX(wdx0b, r, q, actx, p);
        dotH<HH>(wdh0b, r, q, acth0, p);
        bfly(p);
        {   // E1: d, fractional weights, memory term m (batches 2q, 2q+1)
            float s0 = p[2 * q] + bd0r, s1 = p[2 * q + 1] + bd0r;
            float d0 = sigmoid_half(s0), d1 = sigmoid_half(s1);
            float w0 = d0, w1 = d1;
            float2 f = uph(rb0[0]);
            float m0 = d0 * f.x, m1 = d1 * f.y;
#pragma unroll
            for (int k = 1; k < KK; ++k) {
                const float inv = 1.f / (float)(k + 1);
                const float base = (float)k * inv;
                w0 *= fmaf(-d0, inv, base);
                w1 *= fmaf(-d1, inv, base);
                f = uph(rb0[k]);
                m0 = fmaf(w0, f.x, m0);
                m1 = fmaf(w1, f.y, m1);
            }
            repack(packh2(m0, m1), r, q, actm);
        }
        __syncthreads();

        // ---- P2: h0 = tanh(Wx0@x + Wh0@m) ----
#pragma unroll
        for (int b = 0; b < NB; ++b) p[b] = 0.f;
        dotX(wx0b, r, q, actx, p);
        dotH<HH>(wh0b, r, q, actm, p);
        bfly(p);
        {
            float h00 = tanh_fast(p[2 * q] + bh0r);
            float h01 = tanh_fast(p[2 * q + 1] + bh0r);
#pragma unroll
            for (int k = KK - 1; k > 0; --k) rb0[k] = rb0[k - 1];
            rb0[0] = packh2(h00, h01);
            repack(rb0[0], r, q, acth0);
        }
        __syncthreads();

        // ---- P3: o0 = Wo0@h0 + bo0 ----
#pragma unroll
        for (int b = 0; b < NB; ++b) p[b] = 0.f;
        dotH<HH>(wo0b, r, q, acth0, p);
        bfly(p);
        repack(packh2(p[2 * q] + bo0r, p[2 * q + 1] + bo0r), r, q, acto);
        __syncthreads();

        // ---- P4: gate1 = Wdx1@o0 + Wdh1@h1_prev ----
#pragma unroll
        for (int b = 0; b < NB; ++b) p[b] = 0.f;
        dotH<HH>(wdx1b, r, q, acto, p);
        dotH<HH>(wdh1b, r, q, acth1, p);
        bfly(p);
        {
            float s0 = p[2 * q] + bd1r, s1 = p[2 * q + 1] + bd1r;
            float d0 = sigmoid_half(s0), d1 = sigmoid_half(s1);
            float w0 = d0, w1 = d1;
            float2 f = uph(rb1[0]);
            float m0 = d0 * f.x, m1 = d1 * f.y;
#pragma unroll
            for (int k = 1; k < KK; ++k) {
                const float inv = 1.f / (float)(k + 1);
                const float base = (float)k * inv;
                w0 *= fmaf(-d0, inv, base);
                w1 *= fmaf(-d1, inv, base);
                f = uph(rb1[k]);
                m0 = fmaf(w0, f.x, m0);
                m1 = fmaf(w1, f.y, m1);
            }
            repack(packh2(m0, m1), r, q, actm);
        }
        __syncthreads();

        // ---- P5: h1 = tanh(Wx1@o0 + Wh1@m1) ----
#pragma unroll
        for (int b = 0; b < NB; ++b) p[b] = 0.f;
        dotH<HH>(wx1b, r, q, acto, p);
        dotH<HH>(wh1b, r, q, actm, p);
        bfly(p);
        {
            float h10 = tanh_fast(p[2 * q] + bh1r);
            float h11 = tanh_fast(p[2 * q + 1] + bh1r);
#pragma unroll
            for (int k = KK - 1; k > 0; --k) rb1[k] = rb1[k - 1];
            rb1[0] = packh2(h10, h11);
            repack(rb1[0], r, q, acth1);
        }
        __syncthreads();

        // ---- P6: out = Wo1@h1 + bo1  (row r6, chunk c6; reduce over 32 lanes) ----
        {
            float p6[NB];
#pragma unroll
            for (int b = 0; b < NB; ++b) p6[b] = 0.f;
            uint4 w = *(const uint4*)(wo1b + (size_t)(c6 * OUTD + r6) * 8);
            const uint* areg = acth1 + (c6 >> 3) * HSTRIDE + (c6 & 7) * 32;
            dots8(w.x, areg, p6);
            dots8(w.y, areg + 8, p6);
            dots8(w.z, areg + 16, p6);
            dots8(w.w, areg + 24, p6);
#pragma unroll
            for (int b = 0; b < NB; ++b) {
                p6[b] += __shfl_xor(p6[b], 1);
                p6[b] += __shfl_xor(p6[b], 2);
                p6[b] += __shfl_xor(p6[b], 4);
                p6[b] += __shfl_xor(p6[b], 8);
                p6[b] += __shfl_xor(p6[b], 16);
            }
            if (c6 < NB) {
                out[((size_t)t * BB + g * NB + c6) * OUTD + r6] = p6[c6] + bo1r;
            }
        }
        __syncthreads();   // acth1/actx safe before next t's stage/overwrites
    }
}

extern "C" void kernel_launch(void* const* d_in, const int* in_sizes, int n_in,
                              void* d_out, int out_size, void* d_ws, size_t ws_size,
                              hipStream_t stream) {
    const float* inputs = (const float*)d_in[0];
    const float* Wdx0 = (const float*)d_in[1];
    const float* Wdh0 = (const float*)d_in[2];
    const float* bd0  = (const float*)d_in[3];
    const float* Wx0  = (const float*)d_in[4];
    const float* Wh0  = (const float*)d_in[5];
    const float* bh0  = (const float*)d_in[6];
    const float* Wo0  = (const float*)d_in[7];
    const float* bo0  = (const float*)d_in[8];
    const float* Wdx1 = (const float*)d_in[9];
    const float* Wdh1 = (const float*)d_in[10];
    const float* bd1  = (const float*)d_in[11];
    const float* Wx1  = (const float*)d_in[12];
    const float* Wh1  = (const float*)d_in[13];
    const float* bh1  = (const float*)d_in[14];
    const float* Wo1  = (const float*)d_in[15];
    const float* bo1  = (const float*)d_in[16];

    ushort* ws16 = (ushort*)d_ws;

    struct Seg { const float* src; int off, n, lc, cmask, R; };
    const Seg segs[10] = {
        { Wdx0, OFF_WDX0, HH*IN, 5,  31,  HH },
        { Wdh0, OFF_WDH0, HH*HH, 8,  255, HH },
        { Wx0,  OFF_WX0,  HH*IN, 5,  31,  HH },
        { Wh0,  OFF_WH0,  HH*HH, 8,  255, HH },
        { Wo0,  OFF_WO0,  HH*HH, 8,  255, HH },
        { Wdx1, OFF_WDX1, HH*HH, 8,  255, HH },
        { Wdh1, OFF_WDH1, HH*HH, 8,  255, HH },
        { Wx1,  OFF_WX1,  HH*HH, 8,  255, HH },
        { Wh1,  OFF_WH1,  HH*HH, 8,  255, HH },
        { Wo1,  OFF_WO1,  OUTD*HH, 8, 255, OUTD },
    };
    for (int i = 0; i < 10; ++i) {
        int blocks = (segs[i].n + 255) / 256;
        if (blocks > 512) blocks = 512;
        hipLaunchKernelGGL(cvt_f16_T, dim3(blocks), dim3(256), 0, stream,
                           segs[i].src, ws16 + segs[i].off,
                           segs[i].n, segs[i].lc, segs[i].cmask, segs[i].R);
    }

    hipLaunchKernelGGL(mrnn_persist, dim3(NBLK), dim3(NT), 0, stream,
                       (const ushort*)ws16, inputs,
                       bd0, bh0, bo0, bd1, bh1, bo1, (float*)d_out);
}

// Round 11
// 6647.584 us; speedup vs baseline: 6.5531x; 1.4269x over previous
//
#include <hip/hip_runtime.h>
#include <hip/hip_fp16.h>

// Problem dims (fixed by reference)
#define TT 256
#define BB 64
#define IN 32
#define HH 256
#define OUTD 32
#define KK 16
#define NB 8              // batches per block
#define NBLK (BB/NB)      // 8 blocks -> 1 per XCD
#define NT 1024           // 16 waves = 16 row-tiles of 16 rows

// Per-phase A-fragment staging regions (ushort offsets).
// Element (r, k) of a phase matrix [256 x 32*KT]:
//   idx = (((r>>4)*KT + (k>>5))*64 + ((k>>3)&3)*16 + (r&15))*8 + (k&7)
// -> wave rt, k-tile kt: lane l reads 16B at ((rt*KT+kt)*64 + l)*16B  (linear).
#define PB1 0          // [Wdh0 | Wdx0]  KT=9   (16 rt)
#define PB2 73728      // [Wh0  | Wx0 ]  KT=9
#define PB3 147456     // Wo0            KT=8
#define PB4 212992     // [Wdh1 | Wdx1]  KT=16
#define PB5 344064     // [Wh1  | Wx1 ]  KT=16
#define PB6 475136     // Wo1            KT=8   (2 rt)
// total 483328 ushorts = 944 KiB

typedef _Float16 f16x8 __attribute__((ext_vector_type(8)));
typedef float f32x4 __attribute__((ext_vector_type(4)));
union ABu { uint4 u; f16x8 h; };

__global__ void cvt_stage(const float* __restrict__ src, ushort* __restrict__ dst,
                          int n, int lc, int cmask, int KT, int ko) {
    int tid = blockIdx.x * blockDim.x + threadIdx.x;
    int stride = gridDim.x * blockDim.x;
    for (; tid < n; tid += stride) {
        int r = tid >> lc;
        int k = (tid & cmask) + ko;
        int idx = (((r >> 4) * KT + (k >> 5)) * 64 + ((k >> 3) & 3) * 16 + (r & 15)) * 8 + (k & 7);
        dst[idx] = __half_as_ushort(__float2half_rn(src[tid]));
    }
}

__device__ __forceinline__ float2 uph(uint u) {
    union { uint u; _Float16 f[2]; } c; c.u = u;
    return make_float2((float)c.f[0], (float)c.f[1]);
}
__device__ __forceinline__ uint packh2(float a, float b) {
    union { uint u; _Float16 f[2]; } c;
    c.f[0] = (_Float16)a; c.f[1] = (_Float16)b;
    return c.u;
}
__device__ __forceinline__ float tanh_fast(float x) {
    x = fminf(fmaxf(x, -10.f), 10.f);
    float e = __expf(2.f * x);
    return (e - 1.f) / (e + 1.f);
}
__device__ __forceinline__ float sigmoid_half(float x) {   // 0.5*sigmoid(x)
    return 0.5f / (1.f + __expf(-x));
}

// act-staging uint index for k-pair starting at k0 (even), batch col bcol.
// Matches the B-fragment read: tile kt, lane l -> uints (kt&7)*256 + l*4 ..+3
__device__ __forceinline__ int uidx(int k0, int bcol) {
    return (k0 >> 5) * 256 + ((k0 >> 3) & 3) * 64 + bcol * 4 + ((k0 & 7) >> 1);
}

// One phase GEMM: D[16x16] tile for row-tile rt over KT k-tiles.
// A from global (pre-staged fragments), B from LDS (tiles 0-7 bufA, 8-15 bufB).
template<int KT>
__device__ __forceinline__ f32x4 phase_mm(const ushort* __restrict__ wreg,
                                          const uint* bufA, const uint* bufB,
                                          int rt, int l) {
    f32x4 acc = {0.f, 0.f, 0.f, 0.f};
#pragma unroll
    for (int kt = 0; kt < KT; ++kt) {
        ABu a, b;
        a.u = *(const uint4*)(wreg + ((size_t)(rt * KT + kt) * 64 + l) * 8);
        const uint* bp = (kt < 8 ? bufA : bufB) + (kt & 7) * 256 + l * 4;
        b.u = *(const uint4*)bp;
        acc = __builtin_amdgcn_mfma_f32_16x16x32_f16(a.h, b.h, acc, 0, 0, 0);
    }
    return acc;
}

__global__ __launch_bounds__(NT, 4) void mrnn_mfma(
    const ushort* __restrict__ ws16, const float* __restrict__ x_in,
    const float* __restrict__ bd0, const float* __restrict__ bh0, const float* __restrict__ bo0,
    const float* __restrict__ bd1, const float* __restrict__ bh1, const float* __restrict__ bo1,
    float* __restrict__ out)
{
    const int g = blockIdx.x, tid = threadIdx.x;
    const int w = tid >> 6, l = tid & 63;
    const int rg = l >> 4;            // D row-group (rows rg*4..rg*4+3 of tile)
    const int c16 = l & 15;           // D column
    const int bcol = l & 7;           // batch (cols 8-15 mirror 0-7's batch)
    const bool low = c16 < 8;
    const int R0 = w * 16 + rg * 4;   // lane's first D row (P1-P5)
    const int myk0 = R0 + (low ? 0 : 2);  // lane's two owned rows: myk0, myk0+1

    __shared__ __align__(16) uint bufX[256];
    __shared__ __align__(16) uint bufH0[2048], bufM[2048], bufO[2048], bufH1[2048];

    for (int i = tid; i < 2048; i += NT) { bufH0[i] = 0; bufH1[i] = 0; }

    uint r0[KK], r1[KK];   // rings: uint = (h[row a], h[row b]) for lane's 2 rows
#pragma unroll
    for (int k = 0; k < KK; ++k) { r0[k] = 0; r1[k] = 0; }

    if (w == 2) {          // stage x_0
        int o = l >> 4, cc = l & 15;
        if (cc < 8) {
            const float* xp = x_in + ((size_t)0 * BB + g * NB + cc) * IN + o * 8;
            float4 xa = *(const float4*)xp, xb = *(const float4*)(xp + 4);
            uint4 v = make_uint4(packh2(xa.x, xa.y), packh2(xa.z, xa.w),
                                 packh2(xb.x, xb.y), packh2(xb.z, xb.w));
            *(uint4*)&bufX[l * 4] = v;
        }
    }
    __syncthreads();

    for (int t = 0; t < TT; ++t) {
        // ---------- P1: gate0 = [Wdh0|Wdx0] @ [h0_prev; x] ----------
        {
            f32x4 acc = phase_mm<9>(ws16 + PB1, bufH0, bufX, w, l);
            float4 bv = *(const float4*)(bd0 + R0);
            float s0 = acc[0] + bv.x, s1 = acc[1] + bv.y;
            float s2 = acc[2] + bv.z, s3 = acc[3] + bv.w;
            float o2 = __shfl_xor(s2, 8), o3 = __shfl_xor(s3, 8);
            float sa = low ? s0 : o2, sb = low ? s1 : o3;
            float da = sigmoid_half(sa), db = sigmoid_half(sb);
            float wa = da, wb = db;
            float2 f = uph(r0[0]);
            float ma = da * f.x, mb = db * f.y;
#pragma unroll
            for (int k = 1; k < KK; ++k) {
                const float inv = 1.f / (float)(k + 1), base = (float)k * inv;
                wa *= fmaf(-da, inv, base);
                wb *= fmaf(-db, inv, base);
                f = uph(r0[k]);
                ma = fmaf(wa, f.x, ma);
                mb = fmaf(wb, f.y, mb);
            }
            bufM[uidx(myk0, bcol)] = packh2(ma, mb);
        }
        __syncthreads();
        // ---------- P2: h0 = tanh([Wh0|Wx0] @ [m; x] + bh0) ----------
        {
            f32x4 acc = phase_mm<9>(ws16 + PB2, bufM, bufX, w, l);
            float4 bv = *(const float4*)(bh0 + R0);
            float h0 = tanh_fast(acc[0] + bv.x), h1 = tanh_fast(acc[1] + bv.y);
            float h2 = tanh_fast(acc[2] + bv.z), h3 = tanh_fast(acc[3] + bv.w);
            uint hiP = packh2(h2, h3);
            uint rec = (uint)__shfl_xor((int)hiP, 8);
            uint np = low ? packh2(h0, h1) : rec;
#pragma unroll
            for (int k = KK - 1; k > 0; --k) r0[k] = r0[k - 1];
            r0[0] = np;
            if (low) {
                uint2 v = make_uint2(packh2(h0, h1), packh2(h2, h3));
                *(uint2*)&bufH0[uidx(R0, bcol)] = v;
            }
        }
        __syncthreads();
        // ---------- P3: o0 = Wo0 @ h0 + bo0 ----------
        {
            f32x4 acc = phase_mm<8>(ws16 + PB3, bufH0, bufH0, w, l);
            float4 bv = *(const float4*)(bo0 + R0);
            if (low) {
                uint2 v = make_uint2(packh2(acc[0] + bv.x, acc[1] + bv.y),
                                     packh2(acc[2] + bv.z, acc[3] + bv.w));
                *(uint2*)&bufO[uidx(R0, bcol)] = v;
            }
        }
        __syncthreads();
        // ---------- P4: gate1 = [Wdh1|Wdx1] @ [h1_prev; o0] ----------
        {
            f32x4 acc = phase_mm<16>(ws16 + PB4, bufH1, bufO, w, l);
            float4 bv = *(const float4*)(bd1 + R0);
            float s0 = acc[0] + bv.x, s1 = acc[1] + bv.y;
            float s2 = acc[2] + bv.z, s3 = acc[3] + bv.w;
            float o2 = __shfl_xor(s2, 8), o3 = __shfl_xor(s3, 8);
            float sa = low ? s0 : o2, sb = low ? s1 : o3;
            float da = sigmoid_half(sa), db = sigmoid_half(sb);
            float wa = da, wb = db;
            float2 f = uph(r1[0]);
            float ma = da * f.x, mb = db * f.y;
#pragma unroll
            for (int k = 1; k < KK; ++k) {
                const float inv = 1.f / (float)(k + 1), base = (float)k * inv;
                wa *= fmaf(-da, inv, base);
                wb *= fmaf(-db, inv, base);
                f = uph(r1[k]);
                ma = fmaf(wa, f.x, ma);
                mb = fmaf(wb, f.y, mb);
            }
            bufM[uidx(myk0, bcol)] = packh2(ma, mb);
        }
        __syncthreads();
        // ---------- P5: h1 = tanh([Wh1|Wx1] @ [m1; o0] + bh1) ----------
        {
            f32x4 acc = phase_mm<16>(ws16 + PB5, bufM, bufO, w, l);
            float4 bv = *(const float4*)(bh1 + R0);
            float h0 = tanh_fast(acc[0] + bv.x), h1 = tanh_fast(acc[1] + bv.y);
            float h2 = tanh_fast(acc[2] + bv.z), h3 = tanh_fast(acc[3] + bv.w);
            uint hiP = packh2(h2, h3);
            uint rec = (uint)__shfl_xor((int)hiP, 8);
            uint np = low ? packh2(h0, h1) : rec;
#pragma unroll
            for (int k = KK - 1; k > 0; --k) r1[k] = r1[k - 1];
            r1[0] = np;
            if (low) {
                uint2 v = make_uint2(packh2(h0, h1), packh2(h2, h3));
                *(uint2*)&bufH1[uidx(R0, bcol)] = v;
            }
        }
        __syncthreads();
        // ---------- P6: out = Wo1 @ h1 + bo1 (waves 0-1) ; x prefetch (wave 2) ----------
        if (w < 2) {
            f32x4 acc = phase_mm<8>(ws16 + PB6, bufH1, bufH1, w, l);
            if (low) {
                float4 bv = *(const float4*)(bo1 + R0);
                float4 ov = make_float4(acc[0] + bv.x, acc[1] + bv.y,
                                        acc[2] + bv.z, acc[3] + bv.w);
                *(float4*)&out[((size_t)t * BB + g * NB + bcol) * OUTD + R0] = ov;
            }
        } else if (w == 2 && t + 1 < TT) {
            int o = l >> 4, cc = l & 15;
            if (cc < 8) {
                const float* xp = x_in + ((size_t)(t + 1) * BB + g * NB + cc) * IN + o * 8;
                float4 xa = *(const float4*)xp, xb = *(const float4*)(xp + 4);
                uint4 v = make_uint4(packh2(xa.x, xa.y), packh2(xa.z, xa.w),
                                     packh2(xb.x, xb.y), packh2(xb.z, xb.w));
                *(uint4*)&bufX[l * 4] = v;
            }
        }
        __syncthreads();
    }
}

extern "C" void kernel_launch(void* const* d_in, const int* in_sizes, int n_in,
                              void* d_out, int out_size, void* d_ws, size_t ws_size,
                              hipStream_t stream) {
    const float* inputs = (const float*)d_in[0];
    const float* Wdx0 = (const float*)d_in[1];
    const float* Wdh0 = (const float*)d_in[2];
    const float* bd0  = (const float*)d_in[3];
    const float* Wx0  = (const float*)d_in[4];
    const float* Wh0  = (const float*)d_in[5];
    const float* bh0  = (const float*)d_in[6];
    const float* Wo0  = (const float*)d_in[7];
    const float* bo0  = (const float*)d_in[8];
    const float* Wdx1 = (const float*)d_in[9];
    const float* Wdh1 = (const float*)d_in[10];
    const float* bd1  = (const float*)d_in[11];
    const float* Wx1  = (const float*)d_in[12];
    const float* Wh1  = (const float*)d_in[13];
    const float* bh1  = (const float*)d_in[14];
    const float* Wo1  = (const float*)d_in[15];
    const float* bo1  = (const float*)d_in[16];

    ushort* ws16 = (ushort*)d_ws;

    // src, phase base, n, lc(log2 C), cmask, KT, ko (k-offset in phase matrix)
    struct Seg { const float* src; int off, n, lc, cmask, KT, ko; };
    const Seg segs[10] = {
        { Wdh0, PB1, HH*HH,   8, 255, 9,  0   },
        { Wdx0, PB1, HH*IN,   5, 31,  9,  256 },
        { Wh0,  PB2, HH*HH,   8, 255, 9,  0   },
        { Wx0,  PB2, HH*IN,   5, 31,  9,  256 },
        { Wo0,  PB3, HH*HH,   8, 255, 8,  0   },
        { Wdh1, PB4, HH*HH,   8, 255, 16, 0   },
        { Wdx1, PB4, HH*HH,   8, 255, 16, 256 },
        { Wh1,  PB5, HH*HH,   8, 255, 16, 0   },
        { Wx1,  PB5, HH*HH,   8, 255, 16, 256 },
        { Wo1,  PB6, OUTD*HH, 8, 255, 8,  0   },
    };
    for (int i = 0; i < 10; ++i) {
        int blocks = (segs[i].n + 255) / 256;
        if (blocks > 512) blocks = 512;
        hipLaunchKernelGGL(cvt_stage, dim3(blocks), dim3(256), 0, stream,
                           segs[i].src, ws16 + segs[i].off,
                           segs[i].n, segs[i].lc, segs[i].cmask, segs[i].KT, segs[i].ko);
    }

    hipLaunchKernelGGL(mrnn_mfma, dim3(NBLK), dim3(NT), 0, stream,
                       (const ushort*)ws16, inputs,
                       bd0, bh0, bo0, bd1, bh1, bo1, (float*)d_out);
}